// Round 4
// baseline (67.761 us; speedup 1.0000x reference)
//
#include <hip/hip_runtime.h>
#include <math.h>

#define NB 4096
#define ND 512
#define K2 1024
#define NT 16  // K2 / 64 K-tiles

typedef __attribute__((ext_vector_type(8))) short bf16x8;
typedef __attribute__((ext_vector_type(4))) float f32x4;

__device__ __forceinline__ float wave_sum(float v) {
#pragma unroll
  for (int o = 32; o > 0; o >>= 1) v += __shfl_xor(v, o);
  return v;
}

// RNE float->bf16
__device__ __forceinline__ unsigned short f2bf(float x) {
  union { float f; unsigned int u; } c; c.f = x;
  unsigned int u = c.u;
  return (unsigned short)((u + 0x7fffu + ((u >> 16) & 1u)) >> 16);
}

// ---------------------------------------------------------------------------
// Kernel 1: build A=[v_mean|v_sigma], B=[t_mean|t_sigma] in bf16 (4096x1024),
// plus exact f32 row square-norms a_sq[i]=Σ mean² + Σ var (σ²=var).
// ---------------------------------------------------------------------------
__global__ __launch_bounds__(256) void prep_kernel(
    const float* __restrict__ v_mean, const float* __restrict__ v_var,
    const float* __restrict__ t_mean, const float* __restrict__ t_var,
    unsigned short* __restrict__ Abf, unsigned short* __restrict__ Bbf,
    float* __restrict__ a_sq, float* __restrict__ b_sq) {
  int b = blockIdx.x;
  int side = b >> 12;
  int row = b & (NB - 1);
  const float* mean = side ? t_mean : v_mean;
  const float* var = side ? t_var : v_var;
  unsigned short* dst = side ? Bbf : Abf;
  float* sq = side ? b_sq : a_sq;
  int t = threadIdx.x;
  float2 m2 = *(const float2*)(mean + (size_t)row * ND + 2 * t);
  float2 v2 = *(const float2*)(var + (size_t)row * ND + 2 * t);
  float s0 = sqrtf(v2.x), s1 = sqrtf(v2.y);
  ushort2 pm; pm.x = f2bf(m2.x); pm.y = f2bf(m2.y);
  ushort2 ps; ps.x = f2bf(s0); ps.y = f2bf(s1);
  *(ushort2*)(dst + (size_t)row * K2 + 2 * t) = pm;
  *(ushort2*)(dst + (size_t)row * K2 + ND + 2 * t) = ps;
  float p = m2.x * m2.x + m2.y * m2.y + v2.x + v2.y;
  p = wave_sum(p);
  __shared__ float sm[4];
  if ((t & 63) == 0) sm[t >> 6] = p;
  __syncthreads();
  if (t == 0) sq[row] = (sm[0] + sm[1]) + (sm[2] + sm[3]);
}

// ---------------------------------------------------------------------------
// Stage one 128-row REGION of a 256x64 tile (2 loads/thread, 16 KB) into
// linear LDS via global_load_lds, T2 read-swizzle pre-applied on the GLOBAL
// source (rule #21). shift=6: A-region (64-row blocks at off 0/64);
// shift=5: B-region (32-row blocks at off 0/32).
// Region rows match exactly the rows one MFMA quadrant-phase ds_reads.
// ---------------------------------------------------------------------------
__device__ __forceinline__ void stage_region(const unsigned short* __restrict__ G,
                                             int grow0, int k0, unsigned short* lbuf,
                                             int tid, int off, int shift) {
#pragma unroll
  for (int s = 0; s < 2; ++s) {
    int rid = s * 64 + (tid >> 3);
    int row = off + (rid & ((1 << shift) - 1)) + ((rid >> shift) << (shift + 1));
    int q = (tid & 7) * 16;
    int src_b = q ^ ((row & 7) << 4);  // inverse-swizzled source byte
    const unsigned short* ga = G + (size_t)(grow0 + row) * K2 + k0 + (src_b >> 1);
    __builtin_amdgcn_global_load_lds(
        (const __attribute__((address_space(1))) unsigned int*)ga,
        (__attribute__((address_space(3))) unsigned int*)((char*)lbuf + row * 128 + (tid & 7) * 16),
        16, 0, 0);
  }
}

// Swizzled fragment read: logical (row, kbyte) -> physical row*128 + (kb ^ sw).
__device__ __forceinline__ bf16x8 lds_frag(const unsigned short* buf, int row, int kb) {
  return *(const bf16x8*)((const char*)buf + row * 128 + (kb ^ ((row & 7) << 4)));
}

#define READ_A(dst, buf, mh)                                                   \
  _Pragma("unroll") for (int mi = 0; mi < 4; ++mi)                             \
  _Pragma("unroll") for (int ks = 0; ks < 2; ++ks)                             \
      dst[mi][ks] = lds_frag(buf, wr * 128 + (mh) * 64 + mi * 16 + lr, ks * 64 + lk * 16);

#define READ_B(dst, buf, nh)                                                   \
  _Pragma("unroll") for (int ni = 0; ni < 2; ++ni)                             \
  _Pragma("unroll") for (int ks = 0; ks < 2; ++ks)                             \
      dst[ni][ks] = lds_frag(buf, wc * 64 + (nh) * 32 + ni * 16 + lr, ks * 64 + lk * 16);

#define MFMA_QUAD(M0, N0, AF, BF)                                              \
  __builtin_amdgcn_s_setprio(1);                                               \
  _Pragma("unroll") for (int mi = 0; mi < 4; ++mi)                             \
  _Pragma("unroll") for (int ni = 0; ni < 2; ++ni)                             \
  _Pragma("unroll") for (int ks = 0; ks < 2; ++ks)                             \
      acc[(M0) + mi][(N0) + ni] = __builtin_amdgcn_mfma_f32_16x16x32_bf16(     \
          AF[mi][ks], BF[ni][ks], acc[(M0) + mi][(N0) + ni], 0, 0, 0);         \
  __builtin_amdgcn_s_setprio(0);

#define PHASE_SYNC()                                                           \
  __builtin_amdgcn_sched_barrier(0);                                           \
  __builtin_amdgcn_s_barrier();                                                \
  asm volatile("s_waitcnt lgkmcnt(0)" ::: "memory");                           \
  __builtin_amdgcn_sched_barrier(0);

#define PHASE_END()                                                            \
  __builtin_amdgcn_sched_barrier(0);                                           \
  __builtin_amdgcn_s_barrier();

// ---------------------------------------------------------------------------
// Kernel 2: 256x256-tile bf16 MFMA GEMM, BK=64, 8 waves (2Mx4N), double-
// buffered LDS (128 KiB), m201-style 8-phase/2-K-tile schedule with counted
// vmcnt(8) at phases 4/8 only, fused online-LSE partials in the epilogue.
// Quadrant order per K-tile: Q00 -> Q01 -> Q11 -> Q10 (min register liveness).
// Region restage happens exactly one phase after its last ds_read.
// ---------------------------------------------------------------------------
__global__ __launch_bounds__(512) void gemm_fused_kernel(
    const unsigned short* __restrict__ Abf, const unsigned short* __restrict__ Bbf,
    const float* __restrict__ a_sq, const float* __restrict__ b_sq,
    const float* __restrict__ log_temp,
    float* __restrict__ rowM, float* __restrict__ rowS,
    float* __restrict__ colM, float* __restrict__ colS,
    float* __restrict__ diag) {
  __shared__ unsigned short ldsA[2][256 * 64];
  __shared__ unsigned short ldsB[2][256 * 64];
  int bid = blockIdx.x;
  // XCD-aware swizzle: 256 blocks, 8 XCDs -> 32 contiguous per XCD (bijective).
  int swz = (bid & 7) * 32 + (bid >> 3);
  int bm = swz >> 4, bn = swz & 15;
  int brow = bm * 256, bcol = bn * 256;
  int tid = threadIdx.x;
  int lane = tid & 63, wid = tid >> 6;
  int wr = wid >> 2, wc = wid & 3;  // 2x4 wave grid
  int lr = lane & 15, lk = lane >> 4;

  f32x4 acc[8][4] = {};

  // Prologue: stage tiles 0 (first 8 loads) and 1 (next 8); wait tile 0.
  stage_region(Abf, brow, 0, ldsA[0], tid, 0, 6);    // A-first  t0
  stage_region(Bbf, bcol, 0, ldsB[0], tid, 0, 5);    // B-first  t0
  stage_region(Bbf, bcol, 0, ldsB[0], tid, 32, 5);   // B-second t0
  stage_region(Abf, brow, 0, ldsA[0], tid, 64, 6);   // A-second t0
  stage_region(Abf, brow, 64, ldsA[1], tid, 0, 6);
  stage_region(Bbf, bcol, 64, ldsB[1], tid, 0, 5);
  stage_region(Bbf, bcol, 64, ldsB[1], tid, 32, 5);
  stage_region(Abf, brow, 64, ldsA[1], tid, 64, 6);
  asm volatile("s_waitcnt vmcnt(8)" ::: "memory");
  __builtin_amdgcn_s_barrier();

  for (int I = 0; I < NT / 2; ++I) {
    const int u = 2 * I;
    const bool st = (u + 2) < NT;
    const int ku2 = (u + 2) * 64, ku3 = (u + 3) * 64;
    bf16x8 afL[4][2], afH[4][2], bfF[2][2], bfS[2][2];

    // ---- P1: reads afL + bfF (buf0, tile u); MFMA Q00 ----
    READ_A(afL, ldsA[0], 0);
    READ_B(bfF, ldsB[0], 0);
    PHASE_SYNC();
    MFMA_QUAD(0, 0, afL, bfF);
    PHASE_END();
    // ---- P2: reads bfS; stage A-first(u+2), B-first(u+2); MFMA Q01 ----
    READ_B(bfS, ldsB[0], 1);
    if (st) {
      stage_region(Abf, brow, ku2, ldsA[0], tid, 0, 6);
      stage_region(Bbf, bcol, ku2, ldsB[0], tid, 0, 5);
    }
    PHASE_SYNC();
    MFMA_QUAD(0, 2, afL, bfS);
    PHASE_END();
    // ---- P3: reads afH; stage B-second(u+2); MFMA Q11 ----
    READ_A(afH, ldsA[0], 1);
    if (st) stage_region(Bbf, bcol, ku2, ldsB[0], tid, 32, 5);
    PHASE_SYNC();
    MFMA_QUAD(4, 2, afH, bfS);
    PHASE_END();
    // ---- P4: stage A-second(u+2); MFMA Q10; counted vmcnt ----
    if (st) stage_region(Abf, brow, ku2, ldsA[0], tid, 64, 6);
    PHASE_SYNC();
    MFMA_QUAD(4, 0, afH, bfF);
    __builtin_amdgcn_sched_barrier(0);
    if (st) { asm volatile("s_waitcnt vmcnt(8)" ::: "memory"); }
    else    { asm volatile("s_waitcnt vmcnt(0)" ::: "memory"); }
    __builtin_amdgcn_s_barrier();

    // ---- P5: reads afL + bfF (buf1, tile u+1); MFMA Q00 ----
    READ_A(afL, ldsA[1], 0);
    READ_B(bfF, ldsB[1], 0);
    PHASE_SYNC();
    MFMA_QUAD(0, 0, afL, bfF);
    PHASE_END();
    // ---- P6: reads bfS; stage A-first(u+3), B-first(u+3); MFMA Q01 ----
    READ_B(bfS, ldsB[1], 1);
    if (st) {
      stage_region(Abf, brow, ku3, ldsA[1], tid, 0, 6);
      stage_region(Bbf, bcol, ku3, ldsB[1], tid, 0, 5);
    }
    PHASE_SYNC();
    MFMA_QUAD(0, 2, afL, bfS);
    PHASE_END();
    // ---- P7: reads afH; stage B-second(u+3); MFMA Q11 ----
    READ_A(afH, ldsA[1], 1);
    if (st) stage_region(Bbf, bcol, ku3, ldsB[1], tid, 32, 5);
    PHASE_SYNC();
    MFMA_QUAD(4, 2, afH, bfS);
    PHASE_END();
    // ---- P8: stage A-second(u+3); MFMA Q10; counted vmcnt ----
    if (st) stage_region(Abf, brow, ku3, ldsA[1], tid, 64, 6);
    PHASE_SYNC();
    MFMA_QUAD(4, 0, afH, bfF);
    __builtin_amdgcn_sched_barrier(0);
    if (st) { asm volatile("s_waitcnt vmcnt(8)" ::: "memory"); }
    else    { asm volatile("s_waitcnt vmcnt(0)" ::: "memory"); }
    __builtin_amdgcn_s_barrier();
  }

  // ---- epilogue: logits in-place, diag, fused online-LSE partials ----
  float temp = fminf(expf(log_temp[0]), 100.0f);
#pragma unroll
  for (int m = 0; m < 8; ++m) {
#pragma unroll
    for (int r = 0; r < 4; ++r) {
      float asq = a_sq[brow + wr * 128 + m * 16 + lk * 4 + r];
#pragma unroll
      for (int n = 0; n < 4; ++n) {
        float bsq = b_sq[bcol + wc * 64 + n * 16 + lr];
        acc[m][n][r] = -temp * (asq + bsq - 2.0f * acc[m][n][r]);
      }
    }
  }
  if (bm == bn) {
#pragma unroll
    for (int m = 0; m < 8; ++m)
#pragma unroll
      for (int n = 0; n < 4; ++n)
#pragma unroll
        for (int r = 0; r < 4; ++r) {
          int rl = wr * 128 + m * 16 + lk * 4 + r;
          int cl = wc * 64 + n * 16 + lr;
          if (rl == cl) diag[brow + rl] = acc[m][n][r];
        }
  }
  // Row partials: per (m,r): 4 in-lane + reduce across lr (16 lanes).
#pragma unroll
  for (int m = 0; m < 8; ++m) {
#pragma unroll
    for (int r = 0; r < 4; ++r) {
      float mx = fmaxf(fmaxf(acc[m][0][r], acc[m][1][r]),
                       fmaxf(acc[m][2][r], acc[m][3][r]));
#pragma unroll
      for (int o = 1; o < 16; o <<= 1) mx = fmaxf(mx, __shfl_xor(mx, o));
      float s = __expf(acc[m][0][r] - mx) + __expf(acc[m][1][r] - mx) +
                __expf(acc[m][2][r] - mx) + __expf(acc[m][3][r] - mx);
#pragma unroll
      for (int o = 1; o < 16; o <<= 1) s += __shfl_xor(s, o);
      if (lr == 0) {
        int row = brow + wr * 128 + m * 16 + lk * 4 + r;
        int ch = bn * 4 + wc;
        rowM[(size_t)row * 64 + ch] = mx;
        rowS[(size_t)row * 64 + ch] = s;
      }
    }
  }
  // Col partials: per n: 32 in-lane (m,r) + merge lk with lk^1 (xor 16).
#pragma unroll
  for (int n = 0; n < 4; ++n) {
    float mx = -INFINITY;
#pragma unroll
    for (int m = 0; m < 8; ++m)
#pragma unroll
      for (int r = 0; r < 4; ++r) mx = fmaxf(mx, acc[m][n][r]);
    mx = fmaxf(mx, __shfl_xor(mx, 16));
    float s = 0.f;
#pragma unroll
    for (int m = 0; m < 8; ++m)
#pragma unroll
      for (int r = 0; r < 4; ++r) s += __expf(acc[m][n][r] - mx);
    s += __shfl_xor(s, 16);
    if ((lk & 1) == 0) {
      int col = bcol + wc * 64 + n * 16 + lr;
      int ch = bm * 4 + wr * 2 + (lk >> 1);
      colM[(size_t)col * 64 + ch] = mx;
      colS[(size_t)col * 64 + ch] = s;
    }
  }
}

// ---------------------------------------------------------------------------
// Kernel 3: combine 64 chunk-partials per row/col -> (lse - diag).
// ---------------------------------------------------------------------------
__global__ __launch_bounds__(256) void combine_kernel(
    const float* __restrict__ rowM, const float* __restrict__ rowS,
    const float* __restrict__ colM, const float* __restrict__ colS,
    const float* __restrict__ diag, float* __restrict__ hrow,
    float* __restrict__ hcol) {
  int b = blockIdx.x;
  int t = threadIdx.x;
  int wave = t >> 6, lane = t & 63;
  int isCol = b >> 10;
  int idx = (b & 1023) * 4 + wave;
  const float* PM = isCol ? colM : rowM;
  const float* PS = isCol ? colS : rowS;
  float M = PM[(size_t)idx * 64 + lane];
  float S = PS[(size_t)idx * 64 + lane];
#pragma unroll
  for (int o = 1; o < 64; o <<= 1) {
    float M2 = __shfl_xor(M, o), S2 = __shfl_xor(S, o);
    float nM = fmaxf(M, M2);
    S = S * __expf(M - nM) + S2 * __expf(M2 - nM);
    M = nM;
  }
  if (lane == 0) {
    float v = M + logf(S) - diag[idx];
    (isCol ? hcol : hrow)[idx] = v;
  }
}

// Kernel 4: final mean in f64: 0.5*(mean(hrow) + mean(hcol)).
__global__ __launch_bounds__(256) void final_kernel(
    const float* __restrict__ hrow, const float* __restrict__ hcol,
    float* __restrict__ out) {
  int t = threadIdx.x;
  double a = 0.0;
  for (int i = t; i < NB; i += 256) {
    a += 0.5 * ((double)hrow[i] + (double)hcol[i]);
  }
#pragma unroll
  for (int o = 32; o > 0; o >>= 1) a += __shfl_xor(a, o);
  __shared__ double sd[4];
  if ((t & 63) == 0) sd[t >> 6] = a;
  __syncthreads();
  if (t == 0) out[0] = (float)(((sd[0] + sd[1]) + (sd[2] + sd[3])) / (double)NB);
}

extern "C" void kernel_launch(void* const* d_in, const int* in_sizes, int n_in,
                              void* d_out, int out_size, void* d_ws, size_t ws_size,
                              hipStream_t stream) {
  const float* v_mean = (const float*)d_in[0];
  const float* v_var = (const float*)d_in[1];
  const float* t_mean = (const float*)d_in[2];
  const float* t_var = (const float*)d_in[3];
  const float* log_temp = (const float*)d_in[4];
  float* out = (float*)d_out;

  char* ws = (char*)d_ws;
  unsigned short* Abf = (unsigned short*)ws;                     // 8 MiB
  unsigned short* Bbf = (unsigned short*)(ws + 8388608);         // 8 MiB
  float* rowM = (float*)(ws + 16777216);                         // 1 MiB each
  float* rowS = rowM + (size_t)NB * 64;
  float* colM = rowS + (size_t)NB * 64;
  float* colS = colM + (size_t)NB * 64;
  float* diag = colS + (size_t)NB * 64;                          // 16 KiB each
  float* hrow = diag + NB;
  float* hcol = hrow + NB;
  float* a_sq = hcol + NB;
  float* b_sq = a_sq + NB;

  prep_kernel<<<8192, 256, 0, stream>>>(v_mean, v_var, t_mean, t_var, Abf, Bbf, a_sq, b_sq);
  gemm_fused_kernel<<<256, 512, 0, stream>>>(Abf, Bbf, a_sq, b_sq, log_temp,
                                             rowM, rowS, colM, colS, diag);
  combine_kernel<<<2048, 256, 0, stream>>>(rowM, rowS, colM, colS, diag, hrow, hcol);
  final_kernel<<<1, 256, 0, stream>>>(hrow, hcol, out);
}

// Round 5
// 63.947 us; speedup vs baseline: 1.0596x; 1.0596x over previous
//
#include <hip/hip_runtime.h>
#include <math.h>

#define NB 4096
#define ND 512
#define K2 1024
#define NT 16  // K2 / 64 K-tiles

typedef __attribute__((ext_vector_type(8))) short bf16x8;
typedef __attribute__((ext_vector_type(4))) float f32x4;

__device__ __forceinline__ float wave_sum(float v) {
#pragma unroll
  for (int o = 32; o > 0; o >>= 1) v += __shfl_xor(v, o);
  return v;
}

// RNE float->bf16
__device__ __forceinline__ unsigned short f2bf(float x) {
  union { float f; unsigned int u; } c; c.f = x;
  unsigned int u = c.u;
  return (unsigned short)((u + 0x7fffu + ((u >> 16) & 1u)) >> 16);
}

// ---------------------------------------------------------------------------
// Kernel 1: build A=[v_mean|v_sigma], B=[t_mean|t_sigma] in bf16 (4096x1024),
// plus exact f32 row square-norms a_sq[i]=Σ mean² + Σ var (σ²=var).
// ---------------------------------------------------------------------------
__global__ __launch_bounds__(256) void prep_kernel(
    const float* __restrict__ v_mean, const float* __restrict__ v_var,
    const float* __restrict__ t_mean, const float* __restrict__ t_var,
    unsigned short* __restrict__ Abf, unsigned short* __restrict__ Bbf,
    float* __restrict__ a_sq, float* __restrict__ b_sq) {
  int b = blockIdx.x;
  int side = b >> 12;
  int row = b & (NB - 1);
  const float* mean = side ? t_mean : v_mean;
  const float* var = side ? t_var : v_var;
  unsigned short* dst = side ? Bbf : Abf;
  float* sq = side ? b_sq : a_sq;
  int t = threadIdx.x;
  float2 m2 = *(const float2*)(mean + (size_t)row * ND + 2 * t);
  float2 v2 = *(const float2*)(var + (size_t)row * ND + 2 * t);
  float s0 = sqrtf(v2.x), s1 = sqrtf(v2.y);
  ushort2 pm; pm.x = f2bf(m2.x); pm.y = f2bf(m2.y);
  ushort2 ps; ps.x = f2bf(s0); ps.y = f2bf(s1);
  *(ushort2*)(dst + (size_t)row * K2 + 2 * t) = pm;
  *(ushort2*)(dst + (size_t)row * K2 + ND + 2 * t) = ps;
  float p = m2.x * m2.x + m2.y * m2.y + v2.x + v2.y;
  p = wave_sum(p);
  __shared__ float sm[4];
  if ((t & 63) == 0) sm[t >> 6] = p;
  __syncthreads();
  if (t == 0) sq[row] = (sm[0] + sm[1]) + (sm[2] + sm[3]);
}

// Swizzled fragment read: logical (row, kbyte) -> physical row*128 + (kb ^ sw).
__device__ __forceinline__ bf16x8 lds_frag(const unsigned short* buf, int row, int kb) {
  return *(const bf16x8*)((const char*)buf + row * 128 + (kb ^ ((row & 7) << 4)));
}

// ---------------------------------------------------------------------------
// Kernel 2: 128x256-tile bf16 MFMA GEMM, BK=64, 8 waves (2Mx4N, wave=64x64),
// SINGLE-buffered LDS (48 KiB) so 2 blocks co-reside per CU: one block's
// LDS/stage phases overlap the other's MFMA via TLP (m114 mechanism).
// __launch_bounds__(512,4) forces VGPR<=128 -> 16 waves/CU.
// Fused online-LSE partials in the epilogue:
//   rowM/rowS[row][64]  ch = bn*4+wc    colM/colS[col][64]  ch = bm*2+wr
// ---------------------------------------------------------------------------
__global__ __launch_bounds__(512, 4) void gemm_fused_kernel(
    const unsigned short* __restrict__ Abf, const unsigned short* __restrict__ Bbf,
    const float* __restrict__ a_sq, const float* __restrict__ b_sq,
    const float* __restrict__ log_temp,
    float* __restrict__ rowM, float* __restrict__ rowS,
    float* __restrict__ colM, float* __restrict__ colS,
    float* __restrict__ diag) {
  __shared__ unsigned short ldsA[128 * 64];
  __shared__ unsigned short ldsB[256 * 64];
  int bid = blockIdx.x;
  // XCD-aware swizzle: 512 blocks, 8 XCDs -> 64 contiguous per XCD (bijective).
  int swz = (bid & 7) * 64 + (bid >> 3);
  int bm = swz >> 4, bn = swz & 15;       // 32 x 16 grid
  int brow = bm * 128, bcol = bn * 256;
  int tid = threadIdx.x;
  int lane = tid & 63, wid = tid >> 6;
  int wr = wid >> 2, wc = wid & 3;        // 2x4 wave grid, wave = 64x64
  int lr = lane & 15, lk = lane >> 4;

  // Staging offsets: 6 loads/thread (2 for A 128x64, 4 for B 256x64).
  // T2 read-swizzle pre-applied on the GLOBAL source (rule #21): LDS dest is
  // linear (lane-contiguous per wave), source byte = chunk*16 ^ ((row&7)<<4).
  int rbase = tid >> 3, chunk = tid & 7;
  unsigned gofA[2], gofB[4];
  unsigned short* ldA[2];
  unsigned short* ldB[4];
#pragma unroll
  for (int s = 0; s < 2; ++s) {
    int row = s * 64 + rbase;
    gofA[s] = (unsigned)(brow + row) * (K2 * 2) + ((chunk * 16) ^ ((row & 7) << 4));
    ldA[s] = (unsigned short*)((char*)ldsA + row * 128 + chunk * 16);
  }
#pragma unroll
  for (int s = 0; s < 4; ++s) {
    int row = s * 64 + rbase;
    gofB[s] = (unsigned)(bcol + row) * (K2 * 2) + ((chunk * 16) ^ ((row & 7) << 4));
    ldB[s] = (unsigned short*)((char*)ldsB + row * 128 + chunk * 16);
  }

#define STAGE(T)                                                                \
  {                                                                             \
    _Pragma("unroll") for (int s = 0; s < 2; ++s)                               \
        __builtin_amdgcn_global_load_lds(                                       \
            (const __attribute__((address_space(1))) unsigned int*)((const char*)Abf + gofA[s] + (unsigned)(T) * 128), \
            (__attribute__((address_space(3))) unsigned int*)ldA[s], 16, 0, 0); \
    _Pragma("unroll") for (int s = 0; s < 4; ++s)                               \
        __builtin_amdgcn_global_load_lds(                                       \
            (const __attribute__((address_space(1))) unsigned int*)((const char*)Bbf + gofB[s] + (unsigned)(T) * 128), \
            (__attribute__((address_space(3))) unsigned int*)ldB[s], 16, 0, 0); \
  }

  f32x4 acc[4][4] = {};

  // Prologue: stage tile 0, wait, sync.
  STAGE(0);
  asm volatile("s_waitcnt vmcnt(0)" ::: "memory");
  __builtin_amdgcn_s_barrier();

  for (int t = 0; t < NT; ++t) {
    bf16x8 af[4], bf[4];
    // ks=0: read frags + MFMA (compiler inserts precise lgkmcnt; free to
    // interleave ks1 reads into this MFMA region — no sched_barriers).
#pragma unroll
    for (int mi = 0; mi < 4; ++mi)
      af[mi] = lds_frag(ldsA, wr * 64 + mi * 16 + lr, lk * 16);
#pragma unroll
    for (int ni = 0; ni < 4; ++ni)
      bf[ni] = lds_frag(ldsB, wc * 64 + ni * 16 + lr, lk * 16);
    __builtin_amdgcn_s_setprio(1);
#pragma unroll
    for (int mi = 0; mi < 4; ++mi)
#pragma unroll
      for (int ni = 0; ni < 4; ++ni)
        acc[mi][ni] = __builtin_amdgcn_mfma_f32_16x16x32_bf16(af[mi], bf[ni], acc[mi][ni], 0, 0, 0);
    __builtin_amdgcn_s_setprio(0);
    // ks=1: read frags (reuse regs)
    bf16x8 af1[4], bf1[4];
#pragma unroll
    for (int mi = 0; mi < 4; ++mi)
      af1[mi] = lds_frag(ldsA, wr * 64 + mi * 16 + lr, 64 + lk * 16);
#pragma unroll
    for (int ni = 0; ni < 4; ++ni)
      bf1[ni] = lds_frag(ldsB, wc * 64 + ni * 16 + lr, 64 + lk * 16);
    // All this wave's LDS reads done; barrier -> whole tile consumed.
    asm volatile("s_waitcnt lgkmcnt(0)" ::: "memory");
    __builtin_amdgcn_s_barrier();
    // Restage same buffer for tile t+1 (async; lands vmcnt-later).
    if (t + 1 < NT) STAGE(t + 1);
    // ks=1 MFMA on registers, overlapping the stage flight time.
    __builtin_amdgcn_s_setprio(1);
#pragma unroll
    for (int mi = 0; mi < 4; ++mi)
#pragma unroll
      for (int ni = 0; ni < 4; ++ni)
        acc[mi][ni] = __builtin_amdgcn_mfma_f32_16x16x32_bf16(af1[mi], bf1[ni], acc[mi][ni], 0, 0, 0);
    __builtin_amdgcn_s_setprio(0);
    asm volatile("s_waitcnt vmcnt(0)" ::: "memory");
    __builtin_amdgcn_s_barrier();
  }

  // ---- epilogue: logits in-place, diag, fused online-LSE partials ----
  float temp = fminf(expf(log_temp[0]), 100.0f);
#pragma unroll
  for (int m = 0; m < 4; ++m) {
#pragma unroll
    for (int r = 0; r < 4; ++r) {
      float asq = a_sq[brow + wr * 64 + m * 16 + lk * 4 + r];
#pragma unroll
      for (int n = 0; n < 4; ++n) {
        float bsq = b_sq[bcol + wc * 64 + n * 16 + lr];
        acc[m][n][r] = -temp * (asq + bsq - 2.0f * acc[m][n][r]);
      }
    }
  }
  // Diagonal: block contains global diag iff (bm>>1)==bn.
  if ((bm >> 1) == bn) {
#pragma unroll
    for (int m = 0; m < 4; ++m)
#pragma unroll
      for (int n = 0; n < 4; ++n)
#pragma unroll
        for (int r = 0; r < 4; ++r) {
          int rl = wr * 64 + m * 16 + lk * 4 + r;
          int cl = wc * 64 + n * 16 + lr;
          if (brow + rl == bcol + cl) diag[brow + rl] = acc[m][n][r];
        }
  }
  // Row partials: per (m,r): 4 in-lane + reduce across lr (16 lanes).
#pragma unroll
  for (int m = 0; m < 4; ++m) {
#pragma unroll
    for (int r = 0; r < 4; ++r) {
      float mx = fmaxf(fmaxf(acc[m][0][r], acc[m][1][r]),
                       fmaxf(acc[m][2][r], acc[m][3][r]));
#pragma unroll
      for (int o = 1; o < 16; o <<= 1) mx = fmaxf(mx, __shfl_xor(mx, o));
      float s = __expf(acc[m][0][r] - mx) + __expf(acc[m][1][r] - mx) +
                __expf(acc[m][2][r] - mx) + __expf(acc[m][3][r] - mx);
#pragma unroll
      for (int o = 1; o < 16; o <<= 1) s += __shfl_xor(s, o);
      if (lr == 0) {
        int row = brow + wr * 64 + m * 16 + lk * 4 + r;
        int ch = bn * 4 + wc;
        rowM[(size_t)row * 64 + ch] = mx;
        rowS[(size_t)row * 64 + ch] = s;
      }
    }
  }
  // Col partials: per n: 16 in-lane (m,r) + full lk reduce (xor16, xor32).
#pragma unroll
  for (int n = 0; n < 4; ++n) {
    float mx = -INFINITY;
#pragma unroll
    for (int m = 0; m < 4; ++m)
#pragma unroll
      for (int r = 0; r < 4; ++r) mx = fmaxf(mx, acc[m][n][r]);
    mx = fmaxf(mx, __shfl_xor(mx, 16));
    mx = fmaxf(mx, __shfl_xor(mx, 32));
    float s = 0.f;
#pragma unroll
    for (int m = 0; m < 4; ++m)
#pragma unroll
      for (int r = 0; r < 4; ++r) s += __expf(acc[m][n][r] - mx);
    s += __shfl_xor(s, 16);
    s += __shfl_xor(s, 32);
    if (lk == 0) {
      int col = bcol + wc * 64 + n * 16 + lr;
      int ch = bm * 2 + wr;
      colM[(size_t)col * 64 + ch] = mx;
      colS[(size_t)col * 64 + ch] = s;
    }
  }
}

// ---------------------------------------------------------------------------
// Kernel 3: combine 64 chunk-partials per row/col -> (lse - diag).
// ---------------------------------------------------------------------------
__global__ __launch_bounds__(256) void combine_kernel(
    const float* __restrict__ rowM, const float* __restrict__ rowS,
    const float* __restrict__ colM, const float* __restrict__ colS,
    const float* __restrict__ diag, float* __restrict__ hrow,
    float* __restrict__ hcol) {
  int b = blockIdx.x;
  int t = threadIdx.x;
  int wave = t >> 6, lane = t & 63;
  int isCol = b >> 10;
  int idx = (b & 1023) * 4 + wave;
  const float* PM = isCol ? colM : rowM;
  const float* PS = isCol ? colS : rowS;
  float M = PM[(size_t)idx * 64 + lane];
  float S = PS[(size_t)idx * 64 + lane];
#pragma unroll
  for (int o = 1; o < 64; o <<= 1) {
    float M2 = __shfl_xor(M, o), S2 = __shfl_xor(S, o);
    float nM = fmaxf(M, M2);
    S = S * __expf(M - nM) + S2 * __expf(M2 - nM);
    M = nM;
  }
  if (lane == 0) {
    float v = M + logf(S) - diag[idx];
    (isCol ? hcol : hrow)[idx] = v;
  }
}

// Kernel 4: final mean in f64: 0.5*(mean(hrow) + mean(hcol)).
__global__ __launch_bounds__(256) void final_kernel(
    const float* __restrict__ hrow, const float* __restrict__ hcol,
    float* __restrict__ out) {
  int t = threadIdx.x;
  double a = 0.0;
  for (int i = t; i < NB; i += 256) {
    a += 0.5 * ((double)hrow[i] + (double)hcol[i]);
  }
#pragma unroll
  for (int o = 32; o > 0; o >>= 1) a += __shfl_xor(a, o);
  __shared__ double sd[4];
  if ((t & 63) == 0) sd[t >> 6] = a;
  __syncthreads();
  if (t == 0) out[0] = (float)(((sd[0] + sd[1]) + (sd[2] + sd[3])) / (double)NB);
}

extern "C" void kernel_launch(void* const* d_in, const int* in_sizes, int n_in,
                              void* d_out, int out_size, void* d_ws, size_t ws_size,
                              hipStream_t stream) {
  const float* v_mean = (const float*)d_in[0];
  const float* v_var = (const float*)d_in[1];
  const float* t_mean = (const float*)d_in[2];
  const float* t_var = (const float*)d_in[3];
  const float* log_temp = (const float*)d_in[4];
  float* out = (float*)d_out;

  char* ws = (char*)d_ws;
  unsigned short* Abf = (unsigned short*)ws;                     // 8 MiB
  unsigned short* Bbf = (unsigned short*)(ws + 8388608);         // 8 MiB
  float* rowM = (float*)(ws + 16777216);                         // 1 MiB each
  float* rowS = rowM + (size_t)NB * 64;
  float* colM = rowS + (size_t)NB * 64;
  float* colS = colM + (size_t)NB * 64;
  float* diag = colS + (size_t)NB * 64;                          // 16 KiB each
  float* hrow = diag + NB;
  float* hcol = hrow + NB;
  float* a_sq = hcol + NB;
  float* b_sq = a_sq + NB;

  prep_kernel<<<8192, 256, 0, stream>>>(v_mean, v_var, t_mean, t_var, Abf, Bbf, a_sq, b_sq);
  gemm_fused_kernel<<<512, 512, 0, stream>>>(Abf, Bbf, a_sq, b_sq, log_temp,
                                             rowM, rowS, colM, colS, diag);
  combine_kernel<<<2048, 256, 0, stream>>>(rowM, rowS, colM, colS, diag, hrow, hcol);
  final_kernel<<<1, 256, 0, stream>>>(hrow, hcol, out);
}